// Round 14
// baseline (3553.709 us; speedup 1.0000x reference)
//
#include <hip/hip_runtime.h>
#include <math.h>

typedef _Float16 f16;
typedef _Float16 f16x8 __attribute__((ext_vector_type(8)));
typedef float f32x4 __attribute__((ext_vector_type(4)));

namespace {

constexpr int NT = 256;     // 4 waves = 4 column-quarters; 2 blocks/CU (66 KB LDS)
constexpr int M  = 64;      // agents per block
constexpr int HORIZON = 64;

// packed f16 weight layout in d_ws (f16 units); per-chunk fragment order [q][col][j]
constexpr int W2H = 0;        // 65536 f16
constexpr int W2L = 65536;
constexpr int W3H = 131072;
constexpr int W3L = 196608;
constexpr int W1H = 262144;   // 8192 f16 (K padded 13->32)
constexpr int W1L = 270336;   // total 278528 f16 = 544 KB

// ---------------- weight pre-split + pre-pack (once per launch) ----------------
__global__ void prep_kernel(const float* __restrict__ w1, const float* __restrict__ w2,
                            const float* __restrict__ w3, f16* __restrict__ out)
{
    int tid = blockIdx.x * blockDim.x + threadIdx.x;   // 544*256 = 139264 exact
    float v; int hi, lo;
    if (tid < 65536) {          // w2
        int kc = tid >> 13, e2 = tid & 8191;
        int qq = e2 >> 11, col = (e2 >> 3) & 255, j = e2 & 7;
        v = w2[(kc*32 + qq*8 + j)*256 + col];
        hi = W2H + tid; lo = W2L + tid;
    } else if (tid < 131072) {  // w3
        int e = tid - 65536;
        int kc = e >> 13, e2 = e & 8191;
        int qq = e2 >> 11, col = (e2 >> 3) & 255, j = e2 & 7;
        v = w3[(kc*32 + qq*8 + j)*256 + col];
        hi = W3H + e; lo = W3L + e;
    } else {                    // w1, zero-padded to k=32
        int e = tid - 131072;
        int qq = e >> 11, col = (e >> 3) & 255, j = e & 7;
        int k = qq*8 + j;
        v = (k < 13) ? w1[k*256 + col] : 0.f;
        hi = W1H + e; lo = W1L + e;
    }
    f16 h = (f16)v;
    out[hi] = h;
    out[lo] = (f16)(v - (float)h);   // exact residual: 3-term MFMA = fp32-equiv
}

__device__ __forceinline__ void mfma3(f32x4& acc, f16x8 ah, f16x8 al, f16x8 bh, f16x8 bl)
{
    acc = __builtin_amdgcn_mfma_f32_16x16x32_f16(ah, bh, acc, 0, 0, 0);
    acc = __builtin_amdgcn_mfma_f32_16x16x32_f16(al, bh, acc, 0, 0, 0);
    acc = __builtin_amdgcn_mfma_f32_16x16x32_f16(ah, bl, acc, 0, 0, 0);
}

// load this wave's packed B-frags (hi+lo) for one 32-K chunk into slot s: 8x 16B loads
#define FETCH_BP(baseH, baseL, kc, s) do {                                   \
    _Pragma("unroll")                                                        \
    for (int _nt = 0; _nt < 4; ++_nt) {                                      \
        int _off = (kc)*8192 + (q*256 + 64*cq + 16*_nt + lr)*8;              \
        FH[s][_nt] = *(const f16x8*)(wp + (baseH) + _off);                   \
        FL[s][_nt] = *(const f16x8*)(wp + (baseL) + _off);                   \
    }                                                                        \
} while (0)

// one K-chunk: per-mt transient A-frags, B straight from slot s; 48 MFMA
#define GEMM_CHUNK(s, kcl) do {                                              \
    _Pragma("unroll")                                                        \
    for (int _mt = 0; _mt < 4; ++_mt) {                                      \
        int _row = 16*_mt + lr;                                              \
        int _off = _row*256 + ((((kcl)*4 + q) ^ (_row & 31)) << 3);          \
        f16x8 _ah = *(const f16x8*)(hA_hi + _off);                           \
        f16x8 _al = *(const f16x8*)(hA_lo + _off);                           \
        _Pragma("unroll")                                                    \
        for (int _nt = 0; _nt < 4; ++_nt)                                    \
            mfma3(acc[_mt][_nt], _ah, _al, FH[s][_nt], FL[s][_nt]);          \
    }                                                                        \
} while (0)

#define WRITEBACK_ACC() do {                                                 \
    _Pragma("unroll")                                                        \
    for (int _mt = 0; _mt < 4; ++_mt)                                        \
      _Pragma("unroll")                                                      \
      for (int _nt = 0; _nt < 4; ++_nt)                                      \
        _Pragma("unroll")                                                    \
        for (int _r = 0; _r < 4; ++_r) {                                     \
            float _h = fmaxf(acc[_mt][_nt][_r], 0.f);                        \
            f16 _hi = (f16)_h;                                               \
            f16 _lo = (f16)(_h - (float)_hi);                                \
            int _row = 16*_mt + 4*q + _r;                                    \
            int _col = 64*cq + 16*_nt + lr;                                  \
            int _off = _row*256 + (((_col >> 3) ^ (_row & 31)) << 3) + (_col & 7); \
            hA_hi[_off] = _hi;                                               \
            hA_lo[_off] = _lo;                                               \
        }                                                                    \
} while (0)

#define INIT_ACC(brv) do {                                                   \
    _Pragma("unroll")                                                        \
    for (int _mt = 0; _mt < 4; ++_mt)                                        \
      _Pragma("unroll")                                                      \
      for (int _nt = 0; _nt < 4; ++_nt)                                      \
        acc[_mt][_nt] = (f32x4){(brv)[_nt], (brv)[_nt], (brv)[_nt], (brv)[_nt]}; \
} while (0)

// one obs element: split v into f16 hi/lo directly into the outgoing vectors
#define OBS_ELEM(vec_i, val) do {                                            \
    float _v = (val);                                                        \
    f16 _h = (f16)_v;                                                        \
    _hi[vec_i] = _h;                                                         \
    _lo[vec_i] = (f16)(_v - (float)_h);                                      \
} while (0)

// register-lean obs write: <=16 transient regs (was a 32-float array)
#define OBS_WRITE() do {                                                     \
    float _dx0 = px - 1.75f, _dy0 = py - 1.75f;                              \
    float _dx1 = px - 1.75f, _dy1 = py - 3.75f;                              \
    float _dx2 = px - 3.75f, _dy2 = py - 2.00f;                              \
    f16x8 _hi, _lo;                                                          \
    OBS_ELEM(0, px*0.1f);        OBS_ELEM(1, py*0.1f);                       \
    OBS_ELEM(2, (4.f-px)*0.1f);  OBS_ELEM(3, (3.f-py)*0.1f);                 \
    OBS_ELEM(4, -_dx0*0.1f);     OBS_ELEM(5, -_dy0*0.1f);                    \
    OBS_ELEM(6, -_dx1*0.1f);     OBS_ELEM(7, -_dy1*0.1f);                    \
    *(f16x8*)(hA_hi + t*40) = _hi;                                           \
    *(f16x8*)(hA_lo + t*40) = _lo;                                           \
    OBS_ELEM(0, -_dx2*0.1f);     OBS_ELEM(1, -_dy2*0.1f);                    \
    OBS_ELEM(2, sqrtf(_dx0*_dx0+_dy0*_dy0+1e-9f) - 0.38f);                   \
    OBS_ELEM(3, sqrtf(_dx1*_dx1+_dy1*_dy1+1e-9f) - 0.42f);                   \
    OBS_ELEM(4, sqrtf(_dx2*_dx2+_dy2*_dy2+1e-9f) - 0.34f);                   \
    _hi[5] = (f16)0.f; _lo[5] = (f16)0.f;                                    \
    _hi[6] = (f16)0.f; _lo[6] = (f16)0.f;                                    \
    _hi[7] = (f16)0.f; _lo[7] = (f16)0.f;                                    \
    *(f16x8*)(hA_hi + t*40 + 8) = _hi;                                       \
    *(f16x8*)(hA_lo + t*40 + 8) = _lo;                                       \
    f16x8 _z = {};                                                           \
    *(f16x8*)(hA_hi + t*40 + 16) = _z;  *(f16x8*)(hA_hi + t*40 + 24) = _z;   \
    *(f16x8*)(hA_lo + t*40 + 16) = _z;  *(f16x8*)(hA_lo + t*40 + 24) = _z;   \
} while (0)

__global__ __launch_bounds__(NT, 1)   // 1 wave/EU floor -> full 256-VGPR budget
void rollout_kernel(const float* __restrict__ pos0, const float* __restrict__ wind,
                    const float* __restrict__ b1, const float* __restrict__ b2,
                    const float* __restrict__ b3, const float* __restrict__ wmu,
                    const float* __restrict__ bmu, const f16* __restrict__ wp,
                    float* __restrict__ out)
{
    // activations f16 hi/lo, XOR-chunk swizzle: (row,k)->row*256+((k>>3 ^ (row&31))<<3)+(k&7)
    __shared__ __align__(16) f16 hA_hi[M*256];   // 32 KB
    __shared__ __align__(16) f16 hA_lo[M*256];   // 32 KB
    __shared__ __align__(16) float paL[8*M];     // 2 KB separate -> 66 KB total, 2 blocks/CU

    const int t  = threadIdx.x;
    const int l  = t & 63;
    const int cq = t >> 6;         // wave id = col quarter: cols [64cq, 64cq+64)
    const int lr = l & 15;
    const int q  = l >> 4;

    float b1r[4], b2r[4], b3r[4], wmur[4][2];
    #pragma unroll
    for (int nt = 0; nt < 4; ++nt) {
        int col = 64*cq + 16*nt + lr;
        b1r[nt] = b1[col]; b2r[nt] = b2[col]; b3r[nt] = b3[col];
        wmur[nt][0] = wmu[2*col]; wmur[nt][1] = wmu[2*col + 1];
    }
    const float bm0 = bmu[0], bm1 = bmu[1];

    float px=0.f, py=0.f, wx=0.f, wy=0.f;
    float mx_s=-1e30f, sum_s=0.f, mx_r=-1e30f, sum_r=0.f;
    if (t < M) {
        int g = blockIdx.x*M + t;
        px = pos0[2*g]; py = pos0[2*g+1]; wx = wind[2*g]; wy = wind[2*g+1];
    }

    f16x8 FH[2][4], FL[2][4];   // packed B-frag ping-pong: 64 VGPRs
    f32x4 acc[4][4];            // 64 accumulator regs (AGPR-eligible)

    // ---- priming (steady-state slot map: slot0 = w2c0, slot1 = w1) ----
    FETCH_BP(W2H, W2L, 0, 0);
    FETCH_BP(W1H, W1L, 0, 1);
    if (t < M) { OBS_WRITE(); }

    for (int step = 0; step < HORIZON; ++step) {
        __syncthreads();   // B1: obs visible

        // ---- L1: obs(13 pad 32) x w1 (slot1) ----
        INIT_ACC(b1r);
        #pragma unroll
        for (int mt = 0; mt < 4; ++mt) {
            int off = (16*mt + lr)*40 + q*8;
            f16x8 ah = *(const f16x8*)(hA_hi + off);
            f16x8 al = *(const f16x8*)(hA_lo + off);
            #pragma unroll
            for (int nt = 0; nt < 4; ++nt)
                mfma3(acc[mt][nt], ah, al, FH[1][nt], FL[1][nt]);
        }
        FETCH_BP(W2H, W2L, 1, 1);   // slot1 <- w2 c1 (w1 consumed)
        __syncthreads();   // B2: obs reads done -> hA writable
        WRITEBACK_ACC();   // h1 -> hA
        INIT_ACC(b2r);
        __syncthreads();   // B3: h1 visible

        // ---- unified L2+L3: 16 chunks; barriers only at the h1->h2 switch ----
        #pragma unroll
        for (int g = 0; g < 16; ++g) {
            GEMM_CHUNK(g & 1, g & 7);
            if (g < 6)       { FETCH_BP(W2H, W2L, g + 2, g & 1); }
            else if (g == 6) { FETCH_BP(W3H, W3L, 0, 0); }
            else if (g == 7) { FETCH_BP(W3H, W3L, 1, 1); }
            else if (g < 14) { FETCH_BP(W3H, W3L, g - 6, g & 1); }
            else if (g == 14){ FETCH_BP(W2H, W2L, 0, 0); }     // next step w2c0
            else             { FETCH_BP(W1H, W1L, 0, 1); }     // next step w1
            if (g == 7) {
                __syncthreads();   // B4: h1 reads done
                WRITEBACK_ACC();   // h2 -> hA
                INIT_ACC(b3r);
                __syncthreads();   // B5: h2 visible
            }
        }

        // ---- fused L4: per-mt transient partials -> immediate paL store ----
        #pragma unroll
        for (int mt = 0; mt < 4; ++mt) {
            float p0[4] = {0.f,0.f,0.f,0.f}, p1[4] = {0.f,0.f,0.f,0.f};
            #pragma unroll
            for (int nt = 0; nt < 4; ++nt)
                #pragma unroll
                for (int r = 0; r < 4; ++r) {
                    float h = fmaxf(acc[mt][nt][r], 0.f);
                    p0[r] = fmaf(h, wmur[nt][0], p0[r]);
                    p1[r] = fmaf(h, wmur[nt][1], p1[r]);
                }
            #pragma unroll
            for (int s = 0; s < 4; ++s)
                #pragma unroll
                for (int r = 0; r < 4; ++r) {
                    p0[r] += __shfl_xor(p0[r], 1 << s, 64);
                    p1[r] += __shfl_xor(p1[r], 1 << s, 64);
                }
            if (lr == 0) {   // paL separate: store immediately, no reg hold
                f32x4 v0 = {p0[0], p0[1], p0[2], p0[3]};
                f32x4 v1 = {p1[0], p1[1], p1[2], p1[3]};
                *(f32x4*)&paL[(cq*2 + 0)*M + 16*mt + 4*q] = v0;
                *(f32x4*)&paL[(cq*2 + 1)*M + 16*mt + 4*q] = v1;
            }
        }
        __syncthreads();   // B6: paL visible; all hA reads (L3) done

        // ---- P5 + P0: action, dynamics, STREL, next obs (threads 0..63) ----
        if (t < M) {
            float s0 = bm0, s1 = bm1;
            #pragma unroll
            for (int w = 0; w < 4; ++w) {
                s0 += paL[(w*2 + 0)*M + t];
                s1 += paL[(w*2 + 1)*M + t];
            }
            float ax = fminf(fmaxf(s0, -1.f), 1.f);
            float ay = fminf(fmaxf(s1, -1.f), 1.f);
            float vx = 2.f*ax + wx, vy = 2.f*ay + wy;
            #pragma unroll
            for (int s = 0; s < 4; ++s) {
                px = fminf(fmaxf(px + 0.0625f*vx, -4.f), 10.f);
                py = fminf(fmaxf(py + 0.0625f*vy, -4.f), 10.f);
            }
            float dx0 = px - 1.75f, dy0 = py - 1.75f;
            float dx1 = px - 1.75f, dy1 = py - 3.75f;
            float dx2 = px - 3.75f, dy2 = py - 2.00f;
            float c0 = sqrtf(dx0*dx0+dy0*dy0+1e-9f) - 0.38f;
            float c1 = sqrtf(dx1*dx1+dy1*dy1+1e-9f) - 0.42f;
            float c2 = sqrtf(dx2*dx2+dy2*dy2+1e-9f) - 0.34f;
            float cmin = fminf(c0, fminf(c1, c2));
            float ssum = expf(-50.f*(c0-cmin)) + expf(-50.f*(c1-cmin)) + expf(-50.f*(c2-cmin));
            float safe = cmin - logf(ssum)/50.f;
            float gdx = px - 4.f, gdy = py - 3.f;
            float reach = 0.45f - sqrtf(gdx*gdx+gdy*gdy+1e-9f);
            float xs = -8.f*safe;
            if (xs > mx_s) { sum_s = sum_s*expf(mx_s - xs) + 1.f; mx_s = xs; }
            else           { sum_s += expf(xs - mx_s); }
            float xr = 8.f*reach;
            if (xr > mx_r) { sum_r = sum_r*expf(mx_r - xr) + 1.f; mx_r = xr; }
            else           { sum_r += expf(xr - mx_r); }
            OBS_WRITE();   // obs for next step (register-lean)
        }
    }

    if (t < M) {
        float rs = -(mx_s + logf(sum_s)) * 0.125f;
        float rr =  (mx_r + logf(sum_r)) * 0.125f;
        float u0 = -8.f*rs, u1 = -8.f*rr;
        float mu = fmaxf(u0, u1);
        float rho = -(mu + logf(expf(u0-mu) + expf(u1-mu))) * 0.125f;
        out[blockIdx.x*M + t] = rho;
    }
}

} // namespace

extern "C" void kernel_launch(void* const* d_in, const int* in_sizes, int n_in,
                              void* d_out, int out_size, void* d_ws, size_t ws_size,
                              hipStream_t stream)
{
    const float* pos0 = (const float*)d_in[0];
    const float* wind = (const float*)d_in[1];
    const float* w1   = (const float*)d_in[2];
    const float* b1   = (const float*)d_in[3];
    const float* w2   = (const float*)d_in[4];
    const float* b2   = (const float*)d_in[5];
    const float* w3   = (const float*)d_in[6];
    const float* b3   = (const float*)d_in[7];
    const float* wmu  = (const float*)d_in[8];
    const float* bmu  = (const float*)d_in[9];
    float* out = (float*)d_out;
    f16* wp = (f16*)d_ws;   // 278528 f16 = 544 KB packed weights

    prep_kernel<<<544, 256, 0, stream>>>(w1, w2, w3, wp);

    const int B = in_sizes[0] / 2;     // 32768 agents
    const int blocks = B / M;          // 512 blocks, 2/CU, single pass
    rollout_kernel<<<blocks, NT, 0, stream>>>(pos0, wind, b1, b2, b3,
                                              wmu, bmu, wp, out);
}